// Round 8
// baseline (1254.228 us; speedup 1.0000x reference)
//
#include <hip/hip_runtime.h>
#include <math.h>

// Problem dims
#define NB   32      // batch
#define NC   2048    // channels
#define NT   16      // seq len
#define NS   49      // spatial
#define NH   512     // hidden
#define NK1  1024    // fc hidden
#define NOUT 101
#define NTS  784     // NT*NS

#define GB   256     // main grid blocks: 1/CU worst-case -> unconditionally co-resident
#define BT   256     // threads per block
#define NGRP 8       // barrier groups
#define GRPSZ (GB / NGRP)

// workspace layout (float offsets)
#define OF_POOLED 0u        // 65536  : pooled (B,C)
#define OF_TMP    65536u    // 65536  : fc hidden, [path][32][1024]
#define OF_HBUF   131072u   // 32768  : h double buffer, 2 x [32][512]   (row-major, attention)
#define OF_CBUF   163840u   // 16384  : c0 [32][512] (read once into registers)
#define OF_CTXT   180224u   // 65536  : ctx transposed [2048][32]
#define OF_HT     245760u   // 32768  : h transposed double buffer, 2 x [512][32]  (GEMM)
#define OF_HSUM   278528u   // 16384  : sum of h_new over steps [32][512]
#define OF_BAR    294912u   // 320 uints: gen@0, root@32, group q @ 64+32q (128B apart)
#define BAR_N     320

__device__ __forceinline__ float sigf(float x) { return 1.0f / (1.0f + expf(-x)); }

__device__ __forceinline__ float dot4(const float* a, const float* b)
{
    float4 u = *(const float4*)a;
    float4 v = *(const float4*)b;
    return u.x * v.x + u.y * v.y + u.z * v.z + u.w * v.w;
}

__device__ __forceinline__ void fma4(float4& a, float w, const float4& c)
{
    a.x += w * c.x; a.y += w * c.y; a.z += w * c.z; a.w += w * c.w;
}

// async global->LDS, 4B per lane: LDS dest = wave-uniform base + lane*4 (m03 pattern)
__device__ __forceinline__ void gload_lds4(const float* g, float* l)
{
    __builtin_amdgcn_global_load_lds(
        (const __attribute__((address_space(1))) unsigned int*)g,
        (__attribute__((address_space(3))) unsigned int*)l,
        4, 0, 0);
}

// issue the 256ch x 49 float x-slice for (b, chunk, t) into stage[] asynchronously.
// f = tid + 256*q; cc = f/49, s = f%49 kept incrementally (256 = 5*49 + 11).
// wave w iter q covers stage[q*256 + w*64 .. +64) -> uniform LDS base, per-lane gptr.
__device__ __forceinline__ void stage_issue(const float* xb, float* stage, int tid)
{
    int cc = tid / 49;
    int s  = tid - cc * 49;
    float* lbase = stage + (tid & 192);     // w*64, wave-uniform
    #pragma unroll 7
    for (int q = 0; q < 49; ++q) {
        gload_lds4(xb + cc * NTS + s, lbase + q * 256);
        cc += 5; s += 11;
        if (s >= 49) { s -= 49; cc += 1; }
    }
}

// ---------------- pooling kernel: pooled[b,c] = mean over (t,s); also zero barrier ----
extern "C" __global__ __launch_bounds__(BT)
void pool_k(const float* __restrict__ x, float* __restrict__ ws)
{
    if (blockIdx.x == 0) {   // zero ALL barrier state every call (ws is re-poisoned)
        unsigned* bar = (unsigned*)(ws + OF_BAR);
        for (int i = threadIdx.x; i < BAR_N; i += BT)
            __hip_atomic_store(bar + i, 0u, __ATOMIC_RELAXED, __HIP_MEMORY_SCOPE_AGENT);
    }
    int row  = blockIdx.x * 4 + (threadIdx.x >> 6);  // (b*C + c), 65536 rows
    int lane = threadIdx.x & 63;
    const float4* p = (const float4*)(x + (size_t)row * NTS);  // 196 float4, 16B-aligned
    float4 a = p[lane], b = p[lane + 64], c = p[lane + 128];
    float s = a.x + a.y + a.z + a.w + b.x + b.y + b.z + b.w + c.x + c.y + c.z + c.w;
    if (lane < 4) { float4 d = p[192 + lane]; s += d.x + d.y + d.z + d.w; }
    #pragma unroll
    for (int off = 32; off > 0; off >>= 1) s += __shfl_down(s, off, 64);
    if (lane == 0) ws[OF_POOLED + row] = s * (1.0f / 784.0f);
}

// ---------------- two-level device-scope grid barrier ------------------------------
// Arrival: acq_rel RMW on per-group counter (8 lines, 32 arrivals each; release part
// publishes this block's prior stores). Last of a group bumps root (8 arrivals).
// Last at root resets counters and release-stores gen+1. Waiters spin with RELAXED
// loads, then one ACQUIRE load (invalidates stale L1/L2 copies).
// Entry __syncthreads drains vmcnt(0) -> all async stage loads land before arrival.
__device__ __forceinline__ void gbar(float* ws, int blk)
{
    __syncthreads();
    if (threadIdx.x == 0) {
        unsigned* bar  = (unsigned*)(ws + OF_BAR);
        unsigned* gen  = bar;
        unsigned* root = bar + 32;
        unsigned* grp  = bar + 64 + (blk & (NGRP - 1)) * 32;
        unsigned g = __hip_atomic_load(gen, __ATOMIC_RELAXED, __HIP_MEMORY_SCOPE_AGENT);
        unsigned a = __hip_atomic_fetch_add(grp, 1u, __ATOMIC_ACQ_REL, __HIP_MEMORY_SCOPE_AGENT);
        bool done = false;
        if (a == (unsigned)(GRPSZ - 1)) {
            unsigned a2 = __hip_atomic_fetch_add(root, 1u, __ATOMIC_ACQ_REL, __HIP_MEMORY_SCOPE_AGENT);
            if (a2 == (unsigned)(NGRP - 1)) {
                __hip_atomic_store(root, 0u, __ATOMIC_RELAXED, __HIP_MEMORY_SCOPE_AGENT);
                #pragma unroll
                for (int q = 0; q < NGRP; ++q)
                    __hip_atomic_store(bar + 64 + q * 32, 0u, __ATOMIC_RELAXED, __HIP_MEMORY_SCOPE_AGENT);
                __hip_atomic_store(gen, g + 1u, __ATOMIC_RELEASE, __HIP_MEMORY_SCOPE_AGENT);
                done = true;   // root leader synchronized via acquire RMWs
            }
        }
        if (!done) {
            while (__hip_atomic_load(gen, __ATOMIC_RELAXED, __HIP_MEMORY_SCOPE_AGENT) == g)
                __builtin_amdgcn_s_sleep(1);
            (void)__hip_atomic_load(gen, __ATOMIC_ACQUIRE, __HIP_MEMORY_SCOPE_AGENT);
        }
    }
    __syncthreads();
}

// ---------------- main persistent kernel --------------------------------------------
extern "C" __global__ __launch_bounds__(BT)
void main_k(const float* __restrict__ x,
            const float* __restrict__ attw,
            const float* __restrict__ w0h, const float* __restrict__ b0h,
            const float* __restrict__ w1h, const float* __restrict__ b1h,
            const float* __restrict__ w0c, const float* __restrict__ b0c,
            const float* __restrict__ w1c, const float* __restrict__ b1c,
            const float* __restrict__ wih, const float* __restrict__ bih,
            const float* __restrict__ whh, const float* __restrict__ bhh,
            const float* __restrict__ wout, const float* __restrict__ bout,
            float* __restrict__ out, float* __restrict__ ws)
{
    const int tid = threadIdx.x;
    const int blk = blockIdx.x;

    float* pooled = ws + OF_POOLED;
    float* tmp    = ws + OF_TMP;
    float* hbuf   = ws + OF_HBUF;
    float* cbuf   = ws + OF_CBUF;
    float* ctxT   = ws + OF_CTXT;
    float* ht     = ws + OF_HT;
    float* hsum   = ws + OF_HSUM;

    // stage: x-slice [256][49] for the CURRENT step, filled asynchronously one
    // step ahead by global_load_lds (issued in P2, drained at gbar entry).
    __shared__ __align__(16) float  stage[12544];              // 49 KB
    __shared__ __align__(16) float4 red4s[32][2][4][4][2];     // 32 KB K-split partials
    __shared__ float hs[NH];
    __shared__ float al[64];
    __shared__ float gvf[4][2][NB];           // [gate][jj][b]
    float* red = (float*)red4s;               // flat alias for phase 0b (256 floats)

    const int b     = blk & 31;    // P1: batch
    const int chunk = blk >> 5;    // P1: 8 chunks x 256 channels

    // ---- issue t=0 x-slice prefetch; latency hides under phase 0a/0b
    stage_issue(x + (((size_t)b * NC + chunk * 256) * NT + 0) * NS, stage, tid);

    // ---- Phase 0a: tmp[p][m][n] = pooled[m] . w0{h,c}[n] + b  (block = 8 n-rows, all m)
    {
        int p  = blk >> 7;                                // 0: h-path, 1: c-path
        int n  = (blk & 127) * 8 + (tid >> 5);
        int m  = tid & 31;
        const float* W  = p ? w0c : w0h;
        const float* bb = p ? b0c : b0h;
        const float* xr = pooled + m * NC;
        const float* wr = W + (size_t)n * NC;
        float acc = 0.f;
        #pragma unroll 2
        for (int k = 0; k < NC; k += 4) acc += dot4(xr + k, wr + k);
        tmp[p * (NB * NK1) + m * NK1 + n] = acc + bb[n];
    }
    gbar(ws, blk);

    // ---- Phase 0b: h0 = tmp[0] @ w1h.T + b1h ; c0 = tmp[1] @ w1c.T + b1c  (K=1024)
    {
        int p    = blk >> 7;
        int n    = (blk & 127) * 4 + ((tid >> 5) & 3);
        int m    = tid & 31;
        int sspl = tid >> 7;                              // 2-way K split
        const float* W  = p ? w1c : w1h;
        const float* xr = tmp + p * (NB * NK1) + m * NK1 + sspl * (NK1 / 2);
        const float* wr = W + (size_t)n * NK1 + sspl * (NK1 / 2);
        float acc = 0.f;
        #pragma unroll 2
        for (int k = 0; k < NK1 / 2; k += 4) acc += dot4(xr + k, wr + k);
        red[tid] = acc;
        __syncthreads();
        if (sspl == 0) {
            const float* bb = p ? b1c : b1h;
            float v = red[tid] + red[tid + 128] + bb[n];
            if (p == 0) { hbuf[m * NH + n] = v; ht[n * NB + m] = v; }  // h0 (both layouts)
            else        cbuf[m * NH + n] = v;                          // c0
        }
        __syncthreads();
    }
    gbar(ws, blk);

    // ---- persistent per-thread state: pointwise owner (jj,b) fixed across steps
    const int pw_jj = tid >> 5;           // valid for tid < 64
    const int pw_b  = tid & 31;
    const int pw_j  = blk * 2 + pw_jj;
    float c_reg = 0.f, hsum_reg = 0.f;
    if (tid < 64) c_reg = cbuf[pw_b * NH + pw_j];

    // ---- P2 GEMM thread tiling: 4 rows x 8 batches x 32-way K split
    const int ks   = tid >> 3;            // 0..31  K split
    const int rgrp = (tid >> 2) & 1;      // row group: rows rgrp*4 .. +3
    const int bgrp = tid & 3;             // batch group: batches bgrp*8 .. +7
    const int b0   = bgrp * 8;
    const float* wr_[4]; const float* wh_[4];
    #pragma unroll
    for (int ri = 0; ri < 4; ++ri) {
        int ridx = rgrp * 4 + ri;                         // 0..7
        int r = (ridx >> 1) * NH + blk * 2 + (ridx & 1);  // gate row
        wr_[ri] = wih + (size_t)r * NC;
        wh_[ri] = whh + (size_t)r * NH;
    }

    // ---- Scan over T steps: 2 grid barriers per step
    int cur = 0;
    for (int t = 0; t < NT; ++t) {
        float* hc = hbuf + cur * (NB * NH);

        // ---- P1: alpha (redundant per b-block) + ctx gather from prefetched stage
        for (int i = tid; i < NH; i += BT) hs[i] = hc[b * NH + i];
        __syncthreads();
        {   // 49 logits: wave w does s = w, w+4, ...
            int w = tid >> 6, lane = tid & 63;
            for (int s = w; s < NS; s += 4) {
                const float* ar = attw + s * NH;
                float acc = 0.f;
                #pragma unroll
                for (int j = 0; j < 8; ++j) acc += hs[lane + 64 * j] * ar[lane + 64 * j];
                #pragma unroll
                for (int off = 32; off > 0; off >>= 1) acc += __shfl_down(acc, off, 64);
                if (lane == 0) al[s] = acc;
            }
        }
        __syncthreads();
        if (tid < 64) {   // softmax over 49 by wave 0
            float v = (tid < NS) ? al[tid] : -INFINITY;
            float m = v;
            #pragma unroll
            for (int off = 32; off > 0; off >>= 1) m = fmaxf(m, __shfl_down(m, off, 64));
            m = __shfl(m, 0, 64);
            float e = (tid < NS) ? expf(v - m) : 0.f;
            float ssum = e;
            #pragma unroll
            for (int off = 32; off > 0; off >>= 1) ssum += __shfl_down(ssum, off, 64);
            ssum = __shfl(ssum, 0, 64);
            if (tid < NS) {
                float a = e / ssum;
                al[tid] = a;
                if (chunk == 0)
                    __builtin_nontemporal_store(a, &out[NB * NOUT + (b * NT + t) * NS + tid]);
            }
        }
        __syncthreads();
        {   // ctx for channel c = chunk*256 + tid, dotted from LDS stage (stride 49:
            // bank = 17*c+s mod 32 -> 2 lanes/bank = conflict-free)
            int c = chunk * 256 + tid;
            const float* sp = stage + tid * 49;
            float acc = 0.f;
            #pragma unroll
            for (int s = 0; s < NS; ++s) acc += al[s] * sp[s];
            __builtin_nontemporal_store(acc, &ctxT[c * NB + b]);
        }
        gbar(ws, blk);
        // stage reads done (ordered by gbar entry __syncthreads) -> safe to refill

        // ---- P2: block owns 8 gate rows (4 gates x 2 j), all 32 batches.
        {
            // issue t+1 x-slice prefetch; drains at next gbar entry (hidden by GEMM)
            if (t + 1 < NT)
                stage_issue(x + (((size_t)b * NC + chunk * 256) * NT + (t + 1)) * NS,
                            stage, tid);

            const float* hTc = ht + cur * (NH * NB);
            float4 acc[4][2];
            #pragma unroll
            for (int ri = 0; ri < 4; ++ri)
                #pragma unroll
                for (int hh = 0; hh < 2; ++hh)
                    acc[ri][hh] = make_float4(0.f, 0.f, 0.f, 0.f);

            // ctx part: K slice [ks*64, +64)
            int kc0 = ks * 64;
            #pragma unroll 2
            for (int q = 0; q < 16; ++q) {
                int k = kc0 + q * 4;
                float4 w0 = *(const float4*)(wr_[0] + k);
                float4 w1 = *(const float4*)(wr_[1] + k);
                float4 w2 = *(const float4*)(wr_[2] + k);
                float4 w3 = *(const float4*)(wr_[3] + k);
                float wq0[4] = {w0.x, w0.y, w0.z, w0.w};
                float wq1[4] = {w1.x, w1.y, w1.z, w1.w};
                float wq2[4] = {w2.x, w2.y, w2.z, w2.w};
                float wq3[4] = {w3.x, w3.y, w3.z, w3.w};
                #pragma unroll
                for (int kk = 0; kk < 4; ++kk) {
                    const float* cp = ctxT + (size_t)(k + kk) * NB + b0;
                    float4 ca = *(const float4*)cp;
                    float4 cb = *(const float4*)(cp + 4);
                    fma4(acc[0][0], wq0[kk], ca); fma4(acc[0][1], wq0[kk], cb);
                    fma4(acc[1][0], wq1[kk], ca); fma4(acc[1][1], wq1[kk], cb);
                    fma4(acc[2][0], wq2[kk], ca); fma4(acc[2][1], wq2[kk], cb);
                    fma4(acc[3][0], wq3[kk], ca); fma4(acc[3][1], wq3[kk], cb);
                }
            }
            // h part: K slice [ks*16, +16)
            int kh0 = ks * 16;
            #pragma unroll
            for (int q = 0; q < 4; ++q) {
                int k = kh0 + q * 4;
                float4 w0 = *(const float4*)(wh_[0] + k);
                float4 w1 = *(const float4*)(wh_[1] + k);
                float4 w2 = *(const float4*)(wh_[2] + k);
                float4 w3 = *(const float4*)(wh_[3] + k);
                float wq0[4] = {w0.x, w0.y, w0.z, w0.w};
                float wq1[4] = {w1.x, w1.y, w1.z, w1.w};
                float wq2[4] = {w2.x, w2.y, w2.z, w2.w};
                float wq3[4] = {w3.x, w3.y, w3.z, w3.w};
                #pragma unroll
                for (int kk = 0; kk < 4; ++kk) {
                    const float* cp = hTc + (size_t)(k + kk) * NB + b0;
                    float4 ca = *(const float4*)cp;
                    float4 cb = *(const float4*)(cp + 4);
                    fma4(acc[0][0], wq0[kk], ca); fma4(acc[0][1], wq0[kk], cb);
                    fma4(acc[1][0], wq1[kk], ca); fma4(acc[1][1], wq1[kk], cb);
                    fma4(acc[2][0], wq2[kk], ca); fma4(acc[2][1], wq2[kk], cb);
                    fma4(acc[3][0], wq3[kk], ca); fma4(acc[3][1], wq3[kk], cb);
                }
            }
            #pragma unroll
            for (int ri = 0; ri < 4; ++ri) {
                red4s[ks][rgrp][bgrp][ri][0] = acc[ri][0];
                red4s[ks][rgrp][bgrp][ri][1] = acc[ri][1];
            }
            __syncthreads();
            if (tid < 64) {   // reduce 32 K-partials; thread = (row, batch-quad)
                int row = tid >> 3, quad = tid & 7;
                int rg2 = row >> 2, ri2 = row & 3, bg2 = quad >> 1, hh2 = quad & 1;
                float4 s = make_float4(0.f, 0.f, 0.f, 0.f);
                #pragma unroll
                for (int k2 = 0; k2 < 32; ++k2) {
                    float4 v = red4s[k2][rg2][bg2][ri2][hh2];
                    s.x += v.x; s.y += v.y; s.z += v.z; s.w += v.w;
                }
                int g = row >> 1, jj = row & 1;
                int r = g * NH + blk * 2 + jj;
                float bias = bih[r] + bhh[r];
                gvf[g][jj][quad * 4 + 0] = s.x + bias;
                gvf[g][jj][quad * 4 + 1] = s.y + bias;
                gvf[g][jj][quad * 4 + 2] = s.z + bias;
                gvf[g][jj][quad * 4 + 3] = s.w + bias;
            }
            // same wave (wave 0) -> LDS RAW ordered by hardware waitcnt; no barrier needed
            if (tid < 64) {   // LSTM pointwise for (pw_jj, pw_b); c & hsum in registers
                float iv = gvf[0][pw_jj][pw_b], fv = gvf[1][pw_jj][pw_b];
                float gg = gvf[2][pw_jj][pw_b], ov = gvf[3][pw_jj][pw_b];
                float cn = sigf(fv) * c_reg + sigf(iv) * tanhf(gg);
                float hn = sigf(ov) * tanhf(cn);
                c_reg = cn;
                hsum_reg += hn;
                __builtin_nontemporal_store(hn, &hbuf[(cur ^ 1) * (NB * NH) + pw_b * NH + pw_j]);
                __builtin_nontemporal_store(hn, &ht[(cur ^ 1) * (NH * NB) + pw_j * NB + pw_b]);
                if (t == NT - 1)   // publish hsum under the loop's final barrier
                    __builtin_nontemporal_store(hsum_reg, &hsum[pw_b * NH + pw_j]);
            }
        }
        gbar(ws, blk);
        cur ^= 1;
    }

    // final_output = (hsum/16) @ wout.T + bout  (mean over t folded into linear head)
    {
        int w = blk * 4 + (tid >> 6);
        int lane = tid & 63;
        for (int ow = w; ow < NB * NOUT; ow += GB * 4) {
            int bb_ = ow / NOUT, n = ow - bb_ * NOUT;
            const float* hr = hsum + bb_ * NH;
            const float* wr = wout + n * NH;
            float acc = 0.f;
            #pragma unroll
            for (int j = 0; j < 8; ++j) acc += hr[lane + 64 * j] * wr[lane + 64 * j];
            #pragma unroll
            for (int off = 32; off > 0; off >>= 1) acc += __shfl_down(acc, off, 64);
            if (lane == 0) out[bb_ * NOUT + n] = acc * (1.0f / 16.0f) + bout[n];
        }
    }
}

extern "C" void kernel_launch(void* const* d_in, const int* in_sizes, int n_in,
                              void* d_out, int out_size, void* d_ws, size_t ws_size,
                              hipStream_t stream)
{
    (void)in_sizes; (void)n_in; (void)out_size; (void)ws_size;
    const float* x    = (const float*)d_in[0];
    const float* attw = (const float*)d_in[1];
    const float* w0h  = (const float*)d_in[2];
    const float* b0h  = (const float*)d_in[3];
    const float* w1h  = (const float*)d_in[4];
    const float* b1h  = (const float*)d_in[5];
    const float* w0c  = (const float*)d_in[6];
    const float* b0c  = (const float*)d_in[7];
    const float* w1c  = (const float*)d_in[8];
    const float* b1c  = (const float*)d_in[9];
    const float* wih  = (const float*)d_in[10];
    const float* bih  = (const float*)d_in[11];
    const float* whh  = (const float*)d_in[12];
    const float* bhh  = (const float*)d_in[13];
    const float* wout = (const float*)d_in[14];
    const float* bout = (const float*)d_in[15];
    float* out = (float*)d_out;
    float* ws  = (float*)d_ws;

    hipLaunchKernelGGL(pool_k, dim3(16384), dim3(BT), 0, stream, x, ws);
    hipLaunchKernelGGL(main_k, dim3(GB), dim3(BT), 0, stream,
                       x, attw, w0h, b0h, w1h, b1h, w0c, b0c, w1c, b1c,
                       wih, bih, whh, bhh, wout, bout, out, ws);
}